// Round 7
// baseline (48.725 us; speedup 1.0000x reference)
//
#include <hip/hip_runtime.h>
#include <math.h>

#define EPS_F 1e-8f

typedef float vfloat4 __attribute__((ext_vector_type(4)));
// 4-byte-aligned float4: values rows have odd stride (S+1), never 16B-aligned;
// gfx9+ supports dword-aligned multi-dword VMEM.
typedef float uafloat4 __attribute__((ext_vector_type(4), aligned(4)));

// Bit-exact lane-0 broadcast to SGPR. NOTE: __builtin_amdgcn_readfirstlane is
// integer-typed — calling it on float does a NUMERIC float->int conversion
// (R5's correctness bug). Bit-cast explicitly.
__device__ __forceinline__ float bcast0(float x) {
    return __uint_as_float(__builtin_amdgcn_readfirstlane(__float_as_uint(x)));
}

// ---------------------------------------------------------------------------
// One 64-lane wave per batch row, S = 2048 = 8 passes x 256 steps.
// Phase-separated schedule to force deep memory pipelining:
//   Phase 1: ALL 8 passes' loads -> affine coeffs (a,b). 64 persistent VGPRs;
//            all loads in flight together (nothing downstream gates them).
//   Phase 2: 8 INDEPENDENT Kogge-Stone suffix scans (no inter-pass carry) ->
//            per-lane incoming suffix (A1,P1); per-pass composite (pA,pP)
//            broadcast bit-exactly to SGPRs.
//   Phase 3: 8-FMA carry chain for pass boundaries Gb[p], per-element fixup
//            G = A1 + P1*Gb, 4-step replay, nt float4 stores.
// Math per pass (verified R1-R4):
//   a_t = r + gamma(1-d)(1-lam)v_{t+1},  b_t = gamma(1-d)lam,
//   G_t = a_t + b_t G_{t+1};  lane l owns t = p*256 + 4l + j.
// ---------------------------------------------------------------------------
__global__ __launch_bounds__(256) void glam_scan_kernel(
    const float* __restrict__ values,    // B x (S+1), S = 2048
    const float* __restrict__ rewards,   // B x S
    const float* __restrict__ dones,     // B x S
    const float* __restrict__ raw_gamma, // 1
    const float* __restrict__ raw_lambd, // S
    float* __restrict__ out,             // B x S
    int B)
{
    constexpr int S  = 2048;
    constexpr int NP = 8;                // passes of 256 timesteps

    __shared__ float lam_lds[S];

    const int tid  = threadIdx.x;
    const int wave = (blockIdx.x * blockDim.x + tid) >> 6;
    const int lane = tid & 63;

    // ---- Stage lam into LDS (row-independent; tanh once per block) ----
    #pragma unroll
    for (int k = 0; k < S / 256; ++k) {
        const int t = (k << 8) + tid;
        lam_lds[t] = fmaxf(tanhf(raw_lambd[t]), EPS_F);
    }
    __syncthreads();

    if (wave >= B) return;

    const float gamma = fmaxf(tanhf(raw_gamma[0]), EPS_F);

    const size_t vbase = (size_t)wave * (size_t)(S + 1);
    const size_t base  = (size_t)wave * (size_t)S;
    const int lo4 = 4 * lane;

    const float vS = values[vbase + S];  // bootstrap G at t = S

    // ---- Phase 1: all loads -> affine coefficients (a, bb) ----
    float a[NP][4], bb[NP][4];           // static indexing only
    #pragma unroll
    for (int p = 0; p < NP; ++p) {
        const int e0 = (p << 8) + lo4;

        const vfloat4  r4 = *reinterpret_cast<const vfloat4*>(rewards + base + e0);
        const vfloat4  d4 = *reinterpret_cast<const vfloat4*>(dones   + base + e0);
        const uafloat4 v4 = *reinterpret_cast<const uafloat4*>(values + vbase + e0 + 1);
        const vfloat4  l4 = *reinterpret_cast<const vfloat4*>(&lam_lds[e0]);

        const float rr[4] = { r4.x, r4.y, r4.z, r4.w };
        const float dd[4] = { d4.x, d4.y, d4.z, d4.w };
        const float vv[4] = { v4.x, v4.y, v4.z, v4.w };
        const float ll[4] = { l4.x, l4.y, l4.z, l4.w };

        #pragma unroll
        for (int j = 0; j < 4; ++j) {
            const float c = gamma * (1.0f - dd[j]);
            a[p][j]  = fmaf(c * (1.0f - ll[j]), vv[j], rr[j]);
            bb[p][j] = c * ll[j];
        }
    }

    // ---- Phase 2: 8 independent wave suffix scans ----
    float A1[NP], P1[NP];                // incoming suffix (lanes l+1..63)
    float pA[NP], pP[NP];                // per-pass composite (SGPR broadcast)
    #pragma unroll
    for (int p = 0; p < NP; ++p) {
        // Lane-local backward composition over the 4 owned steps.
        float A = 0.0f, P = 1.0f;
        #pragma unroll
        for (int j = 3; j >= 0; --j) {
            A = fmaf(bb[p][j], A, a[p][j]);
            P *= bb[p][j];
        }
        // Kogge-Stone SUFFIX scan: lane l -> composite over lanes l..63.
        #pragma unroll
        for (int d = 1; d < 64; d <<= 1) {
            float A2 = __shfl_down(A, d);
            float P2 = __shfl_down(P, d);
            const bool valid = (lane + d) < 64;
            A2 = valid ? A2 : 0.0f;      // identity beyond the wave
            P2 = valid ? P2 : 1.0f;
            A = fmaf(P, A2, A);
            P *= P2;
        }
        // Full-pass composite = lane 0's result (bit-exact SGPR broadcast).
        pA[p] = bcast0(A);
        pP[p] = bcast0(P);
        // Incoming suffix for this lane (identity for lane 63).
        const float Ad = __shfl_down(A, 1);
        const float Pd = __shfl_down(P, 1);
        A1[p] = (lane == 63) ? 0.0f : Ad;
        P1[p] = (lane == 63) ? 1.0f : Pd;
    }

    // ---- Phase 3: carry chain (8 FMAs), fixup, nt stores ----
    float Gb[NP + 1];                    // Gb[p] = G at t = p*256 (static idx)
    Gb[NP] = vS;
    #pragma unroll
    for (int p = NP - 1; p >= 0; --p)
        Gb[p] = fmaf(pP[p], Gb[p + 1], pA[p]);

    #pragma unroll
    for (int p = 0; p < NP; ++p) {
        float G = fmaf(P1[p], Gb[p + 1], A1[p]);   // G just below this lane's chunk
        float o[4];
        #pragma unroll
        for (int j = 3; j >= 0; --j) {
            G = fmaf(bb[p][j], G, a[p][j]);
            o[j] = G;
        }
        vfloat4 o4;
        o4.x = o[0]; o4.y = o[1]; o4.z = o[2]; o4.w = o[3];
        __builtin_nontemporal_store(o4,
            reinterpret_cast<vfloat4*>(out + base + (p << 8) + lo4));
    }
}

// ---------------------------------------------------------------------------
// Generic fallback (any S): one thread per row, sequential backward scan.
// ---------------------------------------------------------------------------
__global__ void glam_naive_kernel(const float* __restrict__ values,
                                  const float* __restrict__ rewards,
                                  const float* __restrict__ dones,
                                  const float* __restrict__ raw_gamma,
                                  const float* __restrict__ raw_lambd,
                                  float* __restrict__ out, int B, int S) {
    int b = blockIdx.x * blockDim.x + threadIdx.x;
    if (b >= B) return;
    const float gamma = fmaxf(tanhf(raw_gamma[0]), EPS_F);
    const size_t vbase = (size_t)b * (size_t)(S + 1);
    const size_t base  = (size_t)b * (size_t)S;
    float G = values[vbase + S];
    for (int t = S - 1; t >= 0; --t) {
        const float lt = fmaxf(tanhf(raw_lambd[t]), EPS_F);
        const float c  = gamma * (1.0f - dones[base + t]);
        G = rewards[base + t] + c * ((1.0f - lt) * values[vbase + t + 1] + lt * G);
        out[base + t] = G;
    }
}

extern "C" void kernel_launch(void* const* d_in, const int* in_sizes, int n_in,
                              void* d_out, int out_size, void* d_ws, size_t ws_size,
                              hipStream_t stream) {
    const float* values    = (const float*)d_in[0];
    const float* rewards   = (const float*)d_in[1];
    const float* dones     = (const float*)d_in[2];
    const float* raw_gamma = (const float*)d_in[3];
    const float* raw_lambd = (const float*)d_in[4];
    float* out = (float*)d_out;

    const int S = in_sizes[4];            // raw_lambd has S elements
    const int B = in_sizes[1] / S;        // rewards is B*S

    if (S != 2048) {
        // Shape outside the tuned path: correctness fallback.
        glam_naive_kernel<<<(B + 255) / 256, 256, 0, stream>>>(
            values, rewards, dones, raw_gamma, raw_lambd, out, B, S);
        return;
    }

    const int total_threads = B * 64;     // one wave per row
    const int blocks = (total_threads + 255) / 256;

    glam_scan_kernel<<<blocks, 256, 0, stream>>>(
        values, rewards, dones, raw_gamma, raw_lambd, out, B);
}

// Round 8
// 46.675 us; speedup vs baseline: 1.0439x; 1.0439x over previous
//
#include <hip/hip_runtime.h>
#include <math.h>

#define EPS_F 1e-8f

typedef float vfloat4 __attribute__((ext_vector_type(4)));
// 4-byte-aligned float4: values rows have odd stride (S+1), never 16B-aligned;
// gfx9+ supports dword-aligned multi-dword VMEM.
typedef float uafloat4 __attribute__((ext_vector_type(4), aligned(4)));

// Bit-exact lane-0 broadcast to SGPR (readfirstlane is integer-typed; a float
// argument would be NUMERICALLY converted — R5's bug).
__device__ __forceinline__ float bcast0(float x) {
    return __uint_as_float(__builtin_amdgcn_readfirstlane(__float_as_uint(x)));
}

// ---------------------------------------------------------------------------
// S = 2048. TWO waves per row, each owning a 1024-step half (4 passes x 256).
// Block = 256 threads = 4 waves = 2 rows x 2 halves. Halving per-wave serial
// work (4 scans instead of 8) and register demand (a,bb = 32 VGPR) so the
// compiler can keep all of a wave's loads in flight; 2x wave count gives
// finer-grained latency overlap.
//
//   pass p of half h covers t in [h*1024 + p*256, ... +256); lane l owns
//   t = h*1024 + p*256 + 4l + j.
//   a_t = r + gamma(1-d)(1-lam)v_{t+1}, b_t = gamma(1-d)lam,
//   G_t = a_t + b_t G_{t+1}.
// Per pass: lane-local compose -> wave Kogge-Stone SUFFIX scan -> per-lane
// incoming suffix (A1,P1) + pass composite (pA,pP) in SGPRs.
// Upper half composes from vS, writes G(t=1024) to LDS; __syncthreads;
// lower half picks it up. All loads/scans of both halves run pre-sync.
// ---------------------------------------------------------------------------
__global__ __launch_bounds__(256) void glam_scan_kernel(
    const float* __restrict__ values,    // B x (S+1), S = 2048
    const float* __restrict__ rewards,   // B x S
    const float* __restrict__ dones,     // B x S
    const float* __restrict__ raw_gamma, // 1
    const float* __restrict__ raw_lambd, // S
    float* __restrict__ out,             // B x S
    int B)
{
    constexpr int S    = 2048;
    constexpr int HALF = 1024;
    constexpr int NP   = 4;              // passes per half

    __shared__ float lam_lds[S];
    __shared__ float carry_lds[2];       // per-row G at t = HALF

    const int tid  = threadIdx.x;
    const int wib  = tid >> 6;           // wave in block: 0..3
    const int lane = tid & 63;
    const int rib  = wib >> 1;           // row in block: 0..1
    const int half = wib & 1;            // 0 = t<1024, 1 = t>=1024

    // ---- Stage lam into LDS (tanh once per block) ----
    #pragma unroll
    for (int k = 0; k < S / 256; ++k) {
        const int t = (k << 8) + tid;
        lam_lds[t] = fmaxf(tanhf(raw_lambd[t]), EPS_F);
    }
    __syncthreads();

    const int row = blockIdx.x * 2 + rib;

    const float gamma = fmaxf(tanhf(raw_gamma[0]), EPS_F);

    const size_t vbase = (size_t)row * (size_t)(S + 1);
    const size_t base  = (size_t)row * (size_t)S;
    const int t00 = half * HALF;         // wave's base timestep
    const int lo4 = 4 * lane;

    // Bootstrap for the upper half (issued early to hide latency).
    float vS = 0.0f;
    if (half == 1) vS = values[vbase + S];

    // ---- Phase 1: all 4 passes' loads -> affine coefficients (a, bb) ----
    float a[NP][4], bb[NP][4];           // static indexing only
    #pragma unroll
    for (int p = 0; p < NP; ++p) {
        const int e0 = t00 + (p << 8) + lo4;

        const vfloat4  r4 = *reinterpret_cast<const vfloat4*>(rewards + base + e0);
        const vfloat4  d4 = *reinterpret_cast<const vfloat4*>(dones   + base + e0);
        const uafloat4 v4 = *reinterpret_cast<const uafloat4*>(values + vbase + e0 + 1);
        const vfloat4  l4 = *reinterpret_cast<const vfloat4*>(&lam_lds[e0]);

        const float rr[4] = { r4.x, r4.y, r4.z, r4.w };
        const float dd[4] = { d4.x, d4.y, d4.z, d4.w };
        const float vv[4] = { v4.x, v4.y, v4.z, v4.w };
        const float ll[4] = { l4.x, l4.y, l4.z, l4.w };

        #pragma unroll
        for (int j = 0; j < 4; ++j) {
            const float c = gamma * (1.0f - dd[j]);
            a[p][j]  = fmaf(c * (1.0f - ll[j]), vv[j], rr[j]);
            bb[p][j] = c * ll[j];
        }
    }

    // ---- Phase 2: 4 independent wave suffix scans ----
    float A1[NP], P1[NP];                // incoming suffix (lanes l+1..63)
    float pA[NP], pP[NP];                // per-pass composite (SGPR)
    #pragma unroll
    for (int p = 0; p < NP; ++p) {
        float A = 0.0f, P = 1.0f;
        #pragma unroll
        for (int j = 3; j >= 0; --j) {
            A = fmaf(bb[p][j], A, a[p][j]);
            P *= bb[p][j];
        }
        #pragma unroll
        for (int d = 1; d < 64; d <<= 1) {
            float A2 = __shfl_down(A, d);
            float P2 = __shfl_down(P, d);
            const bool valid = (lane + d) < 64;
            A2 = valid ? A2 : 0.0f;      // identity beyond the wave
            P2 = valid ? P2 : 1.0f;
            A = fmaf(P, A2, A);
            P *= P2;
        }
        pA[p] = bcast0(A);
        pP[p] = bcast0(P);
        const float Ad = __shfl_down(A, 1);
        const float Pd = __shfl_down(P, 1);
        A1[p] = (lane == 63) ? 0.0f : Ad;
        P1[p] = (lane == 63) ? 1.0f : Pd;
    }

    // ---- Phase 3: carry chain + cross-wave handoff + fixup + stores ----
    float Gb[NP + 1];                    // Gb[p] = G at t = t00 + p*256

    if (half == 1) {
        Gb[NP] = vS;
        #pragma unroll
        for (int p = NP - 1; p >= 0; --p)
            Gb[p] = fmaf(pP[p], Gb[p + 1], pA[p]);
        if (lane == 0) carry_lds[rib] = Gb[0];   // G at t = 1024
        __syncthreads();
    } else {
        __syncthreads();
        Gb[NP] = carry_lds[rib];
        #pragma unroll
        for (int p = NP - 1; p >= 0; --p)
            Gb[p] = fmaf(pP[p], Gb[p + 1], pA[p]);
    }

    #pragma unroll
    for (int p = 0; p < NP; ++p) {
        float G = fmaf(P1[p], Gb[p + 1], A1[p]);  // G just below lane's chunk
        float o[4];
        #pragma unroll
        for (int j = 3; j >= 0; --j) {
            G = fmaf(bb[p][j], G, a[p][j]);
            o[j] = G;
        }
        vfloat4 o4;
        o4.x = o[0]; o4.y = o[1]; o4.z = o[2]; o4.w = o[3];
        __builtin_nontemporal_store(o4,
            reinterpret_cast<vfloat4*>(out + base + t00 + (p << 8) + lo4));
    }
}

// ---------------------------------------------------------------------------
// Generic fallback (any S, odd B): one thread per row, sequential scan.
// ---------------------------------------------------------------------------
__global__ void glam_naive_kernel(const float* __restrict__ values,
                                  const float* __restrict__ rewards,
                                  const float* __restrict__ dones,
                                  const float* __restrict__ raw_gamma,
                                  const float* __restrict__ raw_lambd,
                                  float* __restrict__ out, int B, int S) {
    int b = blockIdx.x * blockDim.x + threadIdx.x;
    if (b >= B) return;
    const float gamma = fmaxf(tanhf(raw_gamma[0]), EPS_F);
    const size_t vbase = (size_t)b * (size_t)(S + 1);
    const size_t base  = (size_t)b * (size_t)S;
    float G = values[vbase + S];
    for (int t = S - 1; t >= 0; --t) {
        const float lt = fmaxf(tanhf(raw_lambd[t]), EPS_F);
        const float c  = gamma * (1.0f - dones[base + t]);
        G = rewards[base + t] + c * ((1.0f - lt) * values[vbase + t + 1] + lt * G);
        out[base + t] = G;
    }
}

extern "C" void kernel_launch(void* const* d_in, const int* in_sizes, int n_in,
                              void* d_out, int out_size, void* d_ws, size_t ws_size,
                              hipStream_t stream) {
    const float* values    = (const float*)d_in[0];
    const float* rewards   = (const float*)d_in[1];
    const float* dones     = (const float*)d_in[2];
    const float* raw_gamma = (const float*)d_in[3];
    const float* raw_lambd = (const float*)d_in[4];
    float* out = (float*)d_out;

    const int S = in_sizes[4];            // raw_lambd has S elements
    const int B = in_sizes[1] / S;        // rewards is B*S

    if (S != 2048 || (B & 1)) {
        // Shape outside the tuned path: correctness fallback.
        glam_naive_kernel<<<(B + 255) / 256, 256, 0, stream>>>(
            values, rewards, dones, raw_gamma, raw_lambd, out, B, S);
        return;
    }

    const int blocks = B / 2;             // 2 rows per block (4 waves)
    glam_scan_kernel<<<blocks, 256, 0, stream>>>(
        values, rewards, dones, raw_gamma, raw_lambd, out, B);
}